// Round 21
// baseline (63.129 us; speedup 1.0000x reference)
//
#include <hip/hip_runtime.h>
#include <hip/hip_bf16.h>
#include <cstdint>

typedef unsigned short u16;
typedef __attribute__((ext_vector_type(8))) short short8;   // 8 bf16 = 4 VGPR
typedef __attribute__((ext_vector_type(4))) short short4v;  // 4 bf16 = 8B
typedef __attribute__((ext_vector_type(4))) float f32x4;

#define MFMA16(a, b, c) __builtin_amdgcn_mfma_f32_16x16x32_bf16((a), (b), (c), 0, 0, 0)

constexpr int Bn   = 16;
constexpr int Tn   = 2048;
constexpr int Cn   = 384;
constexpr int Hn   = 64;
constexpr long NTOK = (long)Bn * Tn;          // 32768
constexpr long NELT = NTOK * Hn;              // 2,097,152
constexpr int SPLITS = 3;                     // grid 768 = exactly 3 blocks/CU

// Q pre-scale: (1/sqrt(64)) * log2(e), so attention uses bare exp2
#define QSCALE 0.18033688011112042f

// f32 -> bf16 round-to-nearest-even
__device__ __forceinline__ u16 f2bf(float f) {
  union { float f; uint32_t u; } c; c.f = f;
  uint32_t u = c.u;
  return (u16)((u + 0x7fffu + ((u >> 16) & 1u)) >> 16);
}

// pack 2 f32 -> 2 bf16 in one u32 (RNE), gfx950 v_cvt_pk_bf16_f32
__device__ __forceinline__ uint32_t pkbf(float a, float b) {
  uint32_t d;
  asm("v_cvt_pk_bf16_f32 %0, %1, %2" : "=v"(d) : "v"(a), "v"(b));
  return d;
}

// load 8 consecutive f32 and pack to one bf16x8 A-fragment word
__device__ __forceinline__ short8 ldx8(const float* p) {
  const float4 f0 = *reinterpret_cast<const float4*>(p);
  const float4 f1 = *reinterpret_cast<const float4*>(p + 4);
  union { short8 s8; uint32_t u[4]; } r;
  r.u[0] = pkbf(f0.x, f0.y); r.u[1] = pkbf(f0.z, f0.w);
  r.u[2] = pkbf(f1.x, f1.y); r.u[3] = pkbf(f1.z, f1.w);
  return r.s8;
}

// async global->LDS, 16B per lane. LDS dest = wave-uniform base + lane*16.
__device__ __forceinline__ void gl16(const u16* g, const u16* l) {
  __builtin_amdgcn_global_load_lds(
      (const __attribute__((address_space(1))) void*)g,
      (__attribute__((address_space(3))) void*)l, 16, 0, 0);
}

// ---------------------------------------------------------------------------
// Kernel 0: W pre-transpose.  W[384][64] f32 (x3) -> WT[3][64][384] bf16.
// ---------------------------------------------------------------------------
__global__ __launch_bounds__(256) void wtrans(
    const float* __restrict__ Wq, const float* __restrict__ Wk,
    const float* __restrict__ Wv, u16* __restrict__ wtd)
{
  __shared__ u16 tile[64][65];
  const int m  = blockIdx.x / 6;
  const int kc = blockIdx.x % 6;
  const float* W = (m == 0) ? Wq : (m == 1) ? Wk : Wv;
  const int t = threadIdx.x;

  {
    const int kr = t >> 2, seg = t & 3;
    const float* src = W + (size_t)(kc * 64 + kr) * Hn + seg * 16;
    #pragma unroll
    for (int j = 0; j < 4; ++j) {
      const float4 f = *reinterpret_cast<const float4*>(src + j * 4);
      u16* p = &tile[kr][seg * 16 + j * 4];
      p[0] = f2bf(f.x); p[1] = f2bf(f.y); p[2] = f2bf(f.z); p[3] = f2bf(f.w);
    }
  }
  __syncthreads();
  {
    const int hr = t >> 2, seg = t & 3;
    union { short8 s; u16 u[8]; } o0, o1;
    #pragma unroll
    for (int j = 0; j < 8; ++j) o0.u[j] = tile[seg * 16 + j][hr];
    #pragma unroll
    for (int j = 0; j < 8; ++j) o1.u[j] = tile[seg * 16 + 8 + j][hr];
    u16* dst = wtd + ((size_t)m * 64 + hr) * Cn + kc * 64 + seg * 16;
    *reinterpret_cast<short8*>(dst)     = o0.s;
    *reinterpret_cast<short8*>(dst + 8) = o1.s;
  }
}

// ---------------------------------------------------------------------------
// Kernel 1: QKV projection, HIGH-OCCUPANCY variant: 32-row blocks (grid 1024),
// 4 waves = (row-half x col-half); W staged in BK=32 half-chunks, triple-
// buffered 3x12KB = 36 KB -> 4 blocks/CU = 16 waves/CU (2x previous).
// Counted-vmcnt chain: 5 vmem ops/iter (3 gl16 + 2 x-loads); steady vmcnt(7).
// Granule-XOR for 64B rows: c ^= (row>>1)&3 -> 2-way bank access (free).
// ---------------------------------------------------------------------------
__global__ __launch_bounds__(256, 4) void qkv_proj(
    const float* __restrict__ x, const u16* __restrict__ wtd,
    const float* __restrict__ bq, const float* __restrict__ bk,
    const float* __restrict__ bv,
    u16* __restrict__ oq, u16* __restrict__ ok, u16* __restrict__ ovt)
{
  __shared__ u16 wbuf[3][192 * 32];   // 12 KB per buffer (192 rows x 32 cols)

  const int t    = threadIdx.x;
  const int lane = t & 63;
  const int w    = t >> 6;
  const int wr   = w & 1;        // row half: rows wr*16 .. wr*16+15
  const int wc   = w >> 1;       // col half: cols wc*32 .. wc*32+31
  const int l15  = lane & 15;
  const int lh   = lane >> 4;
  const long r0  = (long)blockIdx.x * 32;

  // staging: 768 granules (16B) per half-chunk; thread t does 3.
  // LDS slot (r, c) holds global granule (r, c ^ ((r>>1)&3)).
  int srcoff[3];
  #pragma unroll
  for (int i = 0; i < 3; ++i) {
    const int gid = i * 256 + t;
    const int r = gid >> 2, c = gid & 3;
    srcoff[i] = r * Cn + ((c ^ ((r >> 1) & 3)) << 3);
  }

  const float* xrow = x + (r0 + wr * 16 + l15) * Cn;

  // read-side swizzle: R = 16*A + l15 -> (R>>1)&3 == (l15>>1)&3 (A*8 ≡ 0 mod 4)
  const int cksw = (lh ^ ((l15 >> 1) & 3)) << 3;

  f32x4 acc[3][2];
  #pragma unroll
  for (int m = 0; m < 3; ++m)
    #pragma unroll
    for (int n = 0; n < 2; ++n) acc[m][n] = f32x4{0.f, 0.f, 0.f, 0.f};

  // prologue: stage half-chunks 0,1 (order per chunk: gl16 then x-load)
  #pragma unroll
  for (int i = 0; i < 3; ++i)
    gl16(wtd + srcoff[i], &wbuf[0][(i * 256 + w * 64) * 8]);
  short8 aCur = ldx8(xrow + lh * 8);
  #pragma unroll
  for (int i = 0; i < 3; ++i)
    gl16(wtd + 32 + srcoff[i], &wbuf[1][(i * 256 + w * 64) * 8]);
  short8 aNx1 = ldx8(xrow + 32 + lh * 8);
  short8 aNx2;
  // outstanding: g0(3), x0(2), g1(3), x1(2) -> drain g0 only
  asm volatile("s_waitcnt vmcnt(7)" ::: "memory");
  __builtin_amdgcn_s_barrier();
  __builtin_amdgcn_sched_barrier(0);

  for (int kc = 0; kc < 12; ++kc) {
    const int cb = kc % 3;
    const int sb = (kc + 2) % 3;
    if (kc + 2 < 12) {
      #pragma unroll
      for (int i = 0; i < 3; ++i)
        gl16(wtd + (kc + 2) * 32 + srcoff[i], &wbuf[sb][(i * 256 + w * 64) * 8]);
      aNx2 = ldx8(xrow + (kc + 2) * 32 + lh * 8);
    }

    const u16* wcb = &wbuf[cb][0];
    #pragma unroll
    for (int m = 0; m < 3; ++m)
      #pragma unroll
      for (int n = 0; n < 2; ++n) {
        const int R = m * 64 + wc * 32 + n * 16 + l15;
        const short8 bfr = *reinterpret_cast<const short8*>(&wcb[R * 32 + cksw]);
        acc[m][n] = MFMA16(aCur, bfr, acc[m][n]);
      }

    if (kc + 1 < 12) {
      // drain g(kc+1); leave x(kc+1), g(kc+2), x(kc+2) in flight
      if (kc + 2 < 12) asm volatile("s_waitcnt vmcnt(7)" ::: "memory");
      else             asm volatile("s_waitcnt vmcnt(2)" ::: "memory");
      __builtin_amdgcn_s_barrier();
      __builtin_amdgcn_sched_barrier(0);
      aCur = aNx1;
      aNx1 = aNx2;
    }
  }

  // epilogue: q (scaled) and k row-major; this wave owns (row-half, col-half)
  {
    const float* bias[2] = {bq, bk};
    u16*         dst[2]  = {oq, ok};
    const float  scl[2]  = {QSCALE, 1.0f};
    #pragma unroll
    for (int m = 0; m < 2; ++m) {
      #pragma unroll
      for (int n = 0; n < 2; ++n) {
        int col = wc * 32 + n * 16 + l15;
        float bb = bias[m][col];
        #pragma unroll
        for (int r = 0; r < 4; ++r) {
          int row = lh * 4 + r;
          dst[m][(r0 + wr * 16 + row) * Hn + col] = f2bf((acc[m][n][r] + bb) * scl[m]);
        }
      }
    }
  }
  // v: TRANSPOSED [b][h][t'], t' = tile*64 + PI-slot
  {
    const long g    = r0 + wr * 16 + lh * 4;    // lane's 4 consecutive tokens
    const long bidx = g >> 11;
    const long tloc = g & 2047;
    const int  u    = (int)(tloc & 63);
    const long tb   = tloc & ~63L;
    const int  slotb = 32 * ((u >> 5) & 1) + 8 * ((u >> 2) & 3) + 4 * ((u >> 4) & 1);
    #pragma unroll
    for (int n = 0; n < 2; ++n) {
      int col = wc * 32 + n * 16 + l15;
      float bb = bv[col];
      short4v pk;
      #pragma unroll
      for (int r = 0; r < 4; ++r) pk[r] = (short)f2bf(acc[2][n][r] + bb);
      *reinterpret_cast<short4v*>(ovt + (bidx * Hn + col) * Tn + tb + slotb) = pk;
    }
  }
}

// ---------------------------------------------------------------------------
// Kernel 2: flash attention (byte-identical to R20 measured-best):
// K+V gl16 triple-buffered, counted vmcnt(4), SPLITS=3 (grid 768, no tail),
// 2 q-groups/wave, swapped-QK in-register max-free softmax.
// ---------------------------------------------------------------------------
__global__ __launch_bounds__(256, 3) void flash_attn(
    const u16* __restrict__ q, const u16* __restrict__ k,
    const u16* __restrict__ vt, float* __restrict__ opart,
    float* __restrict__ lpart)
{
  __shared__ u16 kbuf[3][64 * 64];
  __shared__ u16 vbuf[3][64 * 64];

  const int t    = threadIdx.x;
  const int lane = t & 63;
  const int w    = t >> 6;
  const int l15  = lane & 15;
  const int lh   = lane >> 4;
  // XCD swizzle (bijective over 768): each XCD gets 96 consecutive ids
  const int swz_id = (blockIdx.x & 7) * 96 + (blockIdx.x >> 3);
  const int b     = swz_id / 48;
  const int rsw   = swz_id % 48;
  const int split = rsw / 16;
  const int qt    = rsw % 16;
  const long rowbase = (long)b * Tn + qt * 128;
  const int it0 = (split * 32) / 3;          // 0, 10, 21
  const int it1 = ((split + 1) * 32) / 3;    // 10, 21, 32

  short8 aq[2][2];
  #pragma unroll
  for (int qg = 0; qg < 2; ++qg) {
    const u16* qrow = q + (rowbase + w * 32 + qg * 16 + l15) * Hn;
    aq[qg][0] = *reinterpret_cast<const short8*>(qrow + lh * 8);
    aq[qg][1] = *reinterpret_cast<const short8*>(qrow + 32 + lh * 8);
  }

  f32x4 o[2][4];
  #pragma unroll
  for (int qg = 0; qg < 2; ++qg)
    #pragma unroll
    for (int m = 0; m < 4; ++m) o[qg][m] = f32x4{0.f, 0.f, 0.f, 0.f};
  float lacc[2] = {0.f, 0.f};

  const u16* kb_g = k  + (long)b * Tn * Hn;
  const u16* vb_g = vt + (long)b * Hn * Tn;

  // staging: 16B granule-XOR folded into per-lane GLOBAL source (rule #21)
  const int g0 = t, g1 = 256 + t;
  const int r0g = g0 >> 3, c0g = g0 & 7;
  const int r1g = g1 >> 3, c1g = g1 & 7;
  const long ksrc0 = (long)r0g * Hn + ((c0g ^ (r0g & 7)) << 3);
  const long ksrc1 = (long)r1g * Hn + ((c1g ^ (r1g & 7)) << 3);
  const long vsrc0 = (long)r0g * Tn + ((c0g ^ (r0g & 7)) << 3);
  const long vsrc1 = (long)r1g * Tn + ((c1g ^ (r1g & 7)) << 3);
  const int wb0 = w * 64 * 8;
  const int wb1 = wb0 + 256 * 8;

  // fragment-read swizzle
  const int swz  = l15 & 7;
  const int cks0 = ((0 * 4 + lh) ^ swz) << 3;
  const int cks1 = ((1 * 4 + lh) ^ swz) << 3;
  const int rfr  = l15 * 64;

  // prologue: stage tiles it0 -> buf0 and it0+1 -> buf1
  {
    const u16* kt = kb_g + (long)it0 * 64 * Hn;
    const u16* vp = vb_g + it0 * 64;
    gl16(kt + ksrc0, &kbuf[0][wb0]);
    gl16(kt + ksrc1, &kbuf[0][wb1]);
    gl16(vp + vsrc0, &vbuf[0][wb0]);
    gl16(vp + vsrc1, &vbuf[0][wb1]);
    const u16* kt1 = kb_g + (long)(it0 + 1) * 64 * Hn;
    const u16* vp1 = vb_g + (it0 + 1) * 64;
    gl16(kt1 + ksrc0, &kbuf[1][wb0]);
    gl16(kt1 + ksrc1, &kbuf[1][wb1]);
    gl16(vp1 + vsrc0, &vbuf[1][wb0]);
    gl16(vp1 + vsrc1, &vbuf[1][wb1]);
  }
  asm volatile("s_waitcnt vmcnt(4)" ::: "memory");   // tile it0 landed
  __builtin_amdgcn_s_barrier();
  __builtin_amdgcn_sched_barrier(0);

  for (int it = it0; it < it1; ++it) {
    const int cb = (it - it0) % 3;
    const int sb = (it - it0 + 2) % 3;
    if (it + 2 < it1) {
      const u16* kt = kb_g + (long)(it + 2) * 64 * Hn;
      const u16* vp = vb_g + (it + 2) * 64;
      gl16(kt + ksrc0, &kbuf[sb][wb0]);
      gl16(kt + ksrc1, &kbuf[sb][wb1]);
      gl16(vp + vsrc0, &vbuf[sb][wb0]);
      gl16(vp + vsrc1, &vbuf[sb][wb1]);
    }

    const u16* kc  = &kbuf[cb][0];
    const u16* vcb = &vbuf[cb][0];

    // S^T = K Q^T for both q-groups; each K-frag read ONCE
    f32x4 s0[4], s1[4];
    #pragma unroll
    for (int n = 0; n < 4; ++n) { s0[n] = f32x4{0.f,0.f,0.f,0.f}; s1[n] = f32x4{0.f,0.f,0.f,0.f}; }
    #pragma unroll
    for (int n = 0; n < 4; ++n) {
      const short8 ak0 = *reinterpret_cast<const short8*>(&kc[n * 1024 + rfr + cks0]);
      const short8 ak1 = *reinterpret_cast<const short8*>(&kc[n * 1024 + rfr + cks1]);
      s0[n] = MFMA16(ak0, aq[0][0], s0[n]);
      s0[n] = MFMA16(ak1, aq[0][1], s0[n]);
      s1[n] = MFMA16(ak0, aq[1][0], s1[n]);
      s1[n] = MFMA16(ak1, aq[1][1], s1[n]);
    }

    // P = exp2(S) in-register (max-free)
    #pragma unroll
    for (int n = 0; n < 4; ++n)
      #pragma unroll
      for (int r = 0; r < 4; ++r) {
        s0[n][r] = __builtin_amdgcn_exp2f(s0[n][r]);
        s1[n][r] = __builtin_amdgcn_exp2f(s1[n][r]);
      }

    {
      float a0 = (s0[0][0]+s0[0][1])+(s0[0][2]+s0[0][3]);
      float a1 = (s0[1][0]+s0[1][1])+(s0[1][2]+s0[1][3]);
      float a2 = (s0[2][0]+s0[2][1])+(s0[2][2]+s0[2][3]);
      float a3 = (s0[3][0]+s0[3][1])+(s0[3][2]+s0[3][3]);
      lacc[0] += (a0 + a1) + (a2 + a3);
      float b0 = (s1[0][0]+s1[0][1])+(s1[0][2]+s1[0][3]);
      float b1 = (s1[1][0]+s1[1][1])+(s1[1][2]+s1[1][3]);
      float b2 = (s1[2][0]+s1[2][1])+(s1[2][2]+s1[2][3]);
      float b3 = (s1[3][0]+s1[3][1])+(s1[3][2]+s1[3][3]);
      lacc[1] += (b0 + b1) + (b2 + b3);
    }

    union { short8 s8; uint32_t u[4]; } B00, B01, B10, B11;
    B00.u[0] = pkbf(s0[0][0], s0[0][1]); B00.u[1] = pkbf(s0[0][2], s0[0][3]);
    B00.u[2] = pkbf(s0[1][0], s0[1][1]); B00.u[3] = pkbf(s0[1][2], s0[1][3]);
    B01.u[0] = pkbf(s0[2][0], s0[2][1]); B01.u[1] = pkbf(s0[2][2], s0[2][3]);
    B01.u[2] = pkbf(s0[3][0], s0[3][1]); B01.u[3] = pkbf(s0[3][2], s0[3][3]);
    B10.u[0] = pkbf(s1[0][0], s1[0][1]); B10.u[1] = pkbf(s1[0][2], s1[0][3]);
    B10.u[2] = pkbf(s1[1][0], s1[1][1]); B10.u[3] = pkbf(s1[1][2], s1[1][3]);
    B11.u[0] = pkbf(s1[2][0], s1[2][1]); B11.u[1] = pkbf(s1[2][2], s1[2][3]);
    B11.u[2] = pkbf(s1[3][0], s1[3][1]); B11.u[3] = pkbf(s1[3][2], s1[3][3]);

    // O^T += V'^T P^T ; each V-frag read ONCE, used by both q-groups
    #pragma unroll
    for (int m = 0; m < 4; ++m) {
      const short8 av0 = *reinterpret_cast<const short8*>(&vcb[m * 1024 + rfr + cks0]);
      const short8 av1 = *reinterpret_cast<const short8*>(&vcb[m * 1024 + rfr + cks1]);
      o[0][m] = MFMA16(av0, B00.s8, o[0][m]);
      o[0][m] = MFMA16(av1, B01.s8, o[0][m]);
      o[1][m] = MFMA16(av0, B10.s8, o[1][m]);
      o[1][m] = MFMA16(av1, B11.s8, o[1][m]);
    }

    if (it + 1 < it1) {
      // only tile it+1's (older) loads must land; newest 4 may stay in flight
      if (it + 2 < it1) asm volatile("s_waitcnt vmcnt(4)" ::: "memory");
      else              asm volatile("s_waitcnt vmcnt(0)" ::: "memory");
      __builtin_amdgcn_s_barrier();
      __builtin_amdgcn_sched_barrier(0);
    }
  }

  #pragma unroll
  for (int qg = 0; qg < 2; ++qg) {
    float tot = lacc[qg];
    tot += __shfl_xor(tot, 16);
    tot += __shfl_xor(tot, 32);
    const long qrow = rowbase + w * 32 + qg * 16 + l15;
    float* od = opart + ((long)split * NELT) + qrow * Hn;
    #pragma unroll
    for (int m = 0; m < 4; ++m) {
      float4 vv;
      vv.x = o[qg][m][0]; vv.y = o[qg][m][1]; vv.z = o[qg][m][2]; vv.w = o[qg][m][3];
      *reinterpret_cast<float4*>(od + m * 16 + lh * 4) = vv;
    }
    if (lh == 0) lpart[(long)split * NTOK + qrow] = tot;
  }
}

// ---------------------------------------------------------------------------
// Kernel 3: combine split-K partials: out = (sum O_s) / (sum l_s)
// ---------------------------------------------------------------------------
__global__ __launch_bounds__(256) void combine(
    const float* __restrict__ op, const float* __restrict__ lp,
    float* __restrict__ out)
{
  const long idx  = (long)blockIdx.x * 256 + threadIdx.x;
  const long base = idx * 4;
  const long row  = base >> 6;
  float4 acc = *reinterpret_cast<const float4*>(op + base);
  float lsum = lp[row];
  #pragma unroll
  for (int s = 1; s < SPLITS; ++s) {
    const float4 c = *reinterpret_cast<const float4*>(op + s * NELT + base);
    acc.x += c.x; acc.y += c.y; acc.z += c.z; acc.w += c.w;
    lsum += lp[s * NTOK + row];
  }
  const float linv = 1.0f / lsum;
  float4 r;
  r.x = acc.x * linv; r.y = acc.y * linv; r.z = acc.z * linv; r.w = acc.w * linv;
  *reinterpret_cast<float4*>(out + base) = r;
}

// ---------------------------------------------------------------------------
extern "C" void kernel_launch(void* const* d_in, const int* in_sizes, int n_in,
                              void* d_out, int out_size, void* d_ws, size_t ws_size,
                              hipStream_t stream) {
  const float* x  = (const float*)d_in[0];
  const float* Wq = (const float*)d_in[1];
  const float* bq = (const float*)d_in[2];
  const float* Wk = (const float*)d_in[3];
  const float* bk = (const float*)d_in[4];
  const float* Wv = (const float*)d_in[5];
  const float* bv = (const float*)d_in[6];
  float* out = (float*)d_out;

  u16* qs  = (u16*)d_ws;                         // [32768][64] bf16, pre-scaled
  u16* ks  = qs + NELT;                          // [32768][64] bf16
  u16* vs  = ks + NELT;                          // V^T [16][64][2048] bf16 (PI-slot order)
  u16* wtd = vs + NELT;                          // WT [3][64][384] bf16
  float* op = (float*)(wtd + 3 * 64 * Cn);       // O partials [SPLITS][32768][64]
  float* lp = op + (long)SPLITS * NELT;          // l partials [SPLITS][32768]

  hipLaunchKernelGGL(wtrans, dim3(18), dim3(256), 0, stream, Wq, Wk, Wv, wtd);
  hipLaunchKernelGGL(qkv_proj, dim3((int)(NTOK / 32)), dim3(256), 0, stream,
                     x, wtd, bq, bk, bv, qs, ks, vs);
  hipLaunchKernelGGL(flash_attn, dim3(16 * 16 * SPLITS), dim3(256), 0, stream,
                     qs, ks, vs, op, lp);
  hipLaunchKernelGGL(combine, dim3((int)(NELT / 4 / 256)), dim3(256), 0, stream,
                     op, lp, out);
}

// Round 22
// 54.256 us; speedup vs baseline: 1.1635x; 1.1635x over previous
//
#include <hip/hip_runtime.h>
#include <hip/hip_bf16.h>
#include <cstdint>

typedef unsigned short u16;
typedef __attribute__((ext_vector_type(8))) short short8;   // 8 bf16 = 4 VGPR
typedef __attribute__((ext_vector_type(4))) short short4v;  // 4 bf16 = 8B
typedef __attribute__((ext_vector_type(4))) float f32x4;

#define MFMA16(a, b, c) __builtin_amdgcn_mfma_f32_16x16x32_bf16((a), (b), (c), 0, 0, 0)

constexpr int Bn   = 16;
constexpr int Tn   = 2048;
constexpr int Cn   = 384;
constexpr int Hn   = 64;
constexpr long NTOK = (long)Bn * Tn;          // 32768
constexpr long NELT = NTOK * Hn;              // 2,097,152
constexpr int SPLITS = 3;                     // grid 768 = exactly 3 blocks/CU

// Q pre-scale: (1/sqrt(64)) * log2(e), so attention uses bare exp2
#define QSCALE 0.18033688011112042f

// f32 -> bf16 round-to-nearest-even
__device__ __forceinline__ u16 f2bf(float f) {
  union { float f; uint32_t u; } c; c.f = f;
  uint32_t u = c.u;
  return (u16)((u + 0x7fffu + ((u >> 16) & 1u)) >> 16);
}

// pack 2 f32 -> 2 bf16 in one u32 (RNE), gfx950 v_cvt_pk_bf16_f32
__device__ __forceinline__ uint32_t pkbf(float a, float b) {
  uint32_t d;
  asm("v_cvt_pk_bf16_f32 %0, %1, %2" : "=v"(d) : "v"(a), "v"(b));
  return d;
}

// load 8 consecutive f32 and pack to one bf16x8 A-fragment word
__device__ __forceinline__ short8 ldx8(const float* p) {
  const float4 f0 = *reinterpret_cast<const float4*>(p);
  const float4 f1 = *reinterpret_cast<const float4*>(p + 4);
  union { short8 s8; uint32_t u[4]; } r;
  r.u[0] = pkbf(f0.x, f0.y); r.u[1] = pkbf(f0.z, f0.w);
  r.u[2] = pkbf(f1.x, f1.y); r.u[3] = pkbf(f1.z, f1.w);
  return r.s8;
}

// async global->LDS, 16B per lane. LDS dest = wave-uniform base + lane*16.
__device__ __forceinline__ void gl16(const u16* g, const u16* l) {
  __builtin_amdgcn_global_load_lds(
      (const __attribute__((address_space(1))) void*)g,
      (__attribute__((address_space(3))) void*)l, 16, 0, 0);
}

// ---------------------------------------------------------------------------
// Kernel 0: W pre-transpose.  W[384][64] f32 (x3) -> WT[3][64][384] bf16.
// ---------------------------------------------------------------------------
__global__ __launch_bounds__(256) void wtrans(
    const float* __restrict__ Wq, const float* __restrict__ Wk,
    const float* __restrict__ Wv, u16* __restrict__ wtd)
{
  __shared__ u16 tile[64][65];
  const int m  = blockIdx.x / 6;
  const int kc = blockIdx.x % 6;
  const float* W = (m == 0) ? Wq : (m == 1) ? Wk : Wv;
  const int t = threadIdx.x;

  {
    const int kr = t >> 2, seg = t & 3;
    const float* src = W + (size_t)(kc * 64 + kr) * Hn + seg * 16;
    #pragma unroll
    for (int j = 0; j < 4; ++j) {
      const float4 f = *reinterpret_cast<const float4*>(src + j * 4);
      u16* p = &tile[kr][seg * 16 + j * 4];
      p[0] = f2bf(f.x); p[1] = f2bf(f.y); p[2] = f2bf(f.z); p[3] = f2bf(f.w);
    }
  }
  __syncthreads();
  {
    const int hr = t >> 2, seg = t & 3;
    union { short8 s; u16 u[8]; } o0, o1;
    #pragma unroll
    for (int j = 0; j < 8; ++j) o0.u[j] = tile[seg * 16 + j][hr];
    #pragma unroll
    for (int j = 0; j < 8; ++j) o1.u[j] = tile[seg * 16 + 8 + j][hr];
    u16* dst = wtd + ((size_t)m * 64 + hr) * Cn + kc * 64 + seg * 16;
    *reinterpret_cast<short8*>(dst)     = o0.s;
    *reinterpret_cast<short8*>(dst + 8) = o1.s;
  }
}

// ---------------------------------------------------------------------------
// Kernel 1: QKV projection (R20-exact): triple-buffered W gl16 + 2-deep x
// prefetch, counted vmcnt chain.  Grid 512 x 256; LDS 72 KB.
// ---------------------------------------------------------------------------
__global__ __launch_bounds__(256, 2) void qkv_proj(
    const float* __restrict__ x, const u16* __restrict__ wtd,
    const float* __restrict__ bq, const float* __restrict__ bk,
    const float* __restrict__ bv,
    u16* __restrict__ oq, u16* __restrict__ ok, u16* __restrict__ ovt)
{
  __shared__ u16 wbuf[3][3 * 64 * 64];   // 3 x 24 KB, swizzled granules

  const int t    = threadIdx.x;
  const int lane = t & 63;
  const int w    = t >> 6;
  const int l15  = lane & 15;
  const int lh   = lane >> 4;
  const long r0  = (long)blockIdx.x * 64;

  int srcoff[6];
  #pragma unroll
  for (int i = 0; i < 6; ++i) {
    const int g = i * 256 + t;
    const int r = g >> 3, c = g & 7;
    srcoff[i] = r * Cn + ((c ^ (r & 7)) << 3);
  }
  const int ldsb = w * 64 * 8;

  const float* xrow = x + (r0 + w * 16 + l15) * Cn;

  const int cks0 = ((lh)     ^ (l15 & 7)) << 3;
  const int cks1 = ((lh + 4) ^ (l15 & 7)) << 3;

  f32x4 acc[3][4];
  #pragma unroll
  for (int m = 0; m < 3; ++m)
    #pragma unroll
    for (int n = 0; n < 4; ++n) acc[m][n] = f32x4{0.f, 0.f, 0.f, 0.f};

  // prologue: stage W chunks 0,1 ; x chunks 0,1 (issue order: gl16 then x)
  #pragma unroll
  for (int i = 0; i < 6; ++i)
    gl16(wtd + srcoff[i], &wbuf[0][(i * 256) * 8 + ldsb]);
  short8 aCur0 = ldx8(xrow + lh * 8);
  short8 aCur1 = ldx8(xrow + 32 + lh * 8);
  #pragma unroll
  for (int i = 0; i < 6; ++i)
    gl16(wtd + 64 + srcoff[i], &wbuf[1][(i * 256) * 8 + ldsb]);
  short8 aNx10 = ldx8(xrow + 64 + lh * 8);
  short8 aNx11 = ldx8(xrow + 96 + lh * 8);
  short8 aNx20, aNx21;
  asm volatile("s_waitcnt vmcnt(14)" ::: "memory");
  __builtin_amdgcn_s_barrier();
  __builtin_amdgcn_sched_barrier(0);

  for (int kc = 0; kc < 6; ++kc) {
    const int cb = kc % 3;
    const int sb = (kc + 2) % 3;
    if (kc + 2 < 6) {
      #pragma unroll
      for (int i = 0; i < 6; ++i)
        gl16(wtd + (kc + 2) * 64 + srcoff[i], &wbuf[sb][(i * 256) * 8 + ldsb]);
      const float* p = xrow + (kc + 2) * 64 + lh * 8;
      aNx20 = ldx8(p);
      aNx21 = ldx8(p + 32);
    }

    const u16* wc = &wbuf[cb][0];
    #pragma unroll
    for (int m = 0; m < 3; ++m)
      #pragma unroll
      for (int n = 0; n < 4; ++n) {
        const int row = m * 64 + n * 16 + l15;
        const short8 b0 = *reinterpret_cast<const short8*>(&wc[row * 64 + cks0]);
        acc[m][n] = MFMA16(aCur0, b0, acc[m][n]);
        const short8 b1 = *reinterpret_cast<const short8*>(&wc[row * 64 + cks1]);
        acc[m][n] = MFMA16(aCur1, b1, acc[m][n]);
      }

    if (kc + 1 < 6) {
      if (kc + 2 < 6) asm volatile("s_waitcnt vmcnt(14)" ::: "memory");
      else            asm volatile("s_waitcnt vmcnt(4)"  ::: "memory");
      __builtin_amdgcn_s_barrier();
      __builtin_amdgcn_sched_barrier(0);
      aCur0 = aNx10; aCur1 = aNx11;
      aNx10 = aNx20; aNx11 = aNx21;
    }
  }

  // epilogue: q (scaled) and k row-major
  {
    const float* bias[2] = {bq, bk};
    u16*         dst[2]  = {oq, ok};
    const float  scl[2]  = {QSCALE, 1.0f};
    #pragma unroll
    for (int m = 0; m < 2; ++m) {
      #pragma unroll
      for (int n = 0; n < 4; ++n) {
        int col = n * 16 + l15;
        float bb = bias[m][col];
        #pragma unroll
        for (int r = 0; r < 4; ++r) {
          int row = lh * 4 + r;
          dst[m][(r0 + w * 16 + row) * Hn + col] = f2bf((acc[m][n][r] + bb) * scl[m]);
        }
      }
    }
  }
  // v: TRANSPOSED [b][h][t'], t' = tile*64 + PI-slot
  {
    const long g    = r0 + w * 16 + lh * 4;
    const long bidx = g >> 11;
    const long tloc = g & 2047;
    const int  u    = (int)(tloc & 63);
    const long tb   = tloc & ~63L;
    const int  slotb = 32 * ((u >> 5) & 1) + 8 * ((u >> 2) & 3) + 4 * ((u >> 4) & 1);
    #pragma unroll
    for (int n = 0; n < 4; ++n) {
      int col = n * 16 + l15;
      float bb = bv[col];
      short4v pk;
      #pragma unroll
      for (int r = 0; r < 4; ++r) pk[r] = (short)f2bf(acc[2][n][r] + bb);
      *reinterpret_cast<short4v*>(ovt + (bidx * Hn + col) * Tn + tb + slotb) = pk;
    }
  }
}

// ---------------------------------------------------------------------------
// Kernel 2: flash attention (R20 pipeline + ONES-MFMA row-sum):
// K+V gl16 triple-buffered, counted vmcnt(4), SPLITS=3, 2 q-groups/wave.
// l computed on the matrix pipe: MFMA(ones_A, P-frags) -> every lane holds
// the full tile sum for q=l15 (no VALU adds, no epilogue shuffles).
// ---------------------------------------------------------------------------
__global__ __launch_bounds__(256, 3) void flash_attn(
    const u16* __restrict__ q, const u16* __restrict__ k,
    const u16* __restrict__ vt, float* __restrict__ opart,
    float* __restrict__ lpart)
{
  __shared__ u16 kbuf[3][64 * 64];
  __shared__ u16 vbuf[3][64 * 64];

  const int t    = threadIdx.x;
  const int lane = t & 63;
  const int w    = t >> 6;
  const int l15  = lane & 15;
  const int lh   = lane >> 4;
  // XCD swizzle (bijective over 768): each XCD gets 96 consecutive ids
  const int swz_id = (blockIdx.x & 7) * 96 + (blockIdx.x >> 3);
  const int b     = swz_id / 48;
  const int rsw   = swz_id % 48;
  const int split = rsw / 16;
  const int qt    = rsw % 16;
  const long rowbase = (long)b * Tn + qt * 128;
  const int it0 = (split * 32) / 3;          // 0, 10, 21
  const int it1 = ((split + 1) * 32) / 3;    // 10, 21, 32

  short8 aq[2][2];
  #pragma unroll
  for (int qg = 0; qg < 2; ++qg) {
    const u16* qrow = q + (rowbase + w * 32 + qg * 16 + l15) * Hn;
    aq[qg][0] = *reinterpret_cast<const short8*>(qrow + lh * 8);
    aq[qg][1] = *reinterpret_cast<const short8*>(qrow + 32 + lh * 8);
  }

  // all-ones A-fragment (bf16 1.0 splat)
  union { short8 s8; uint32_t u[4]; } ON;
  #pragma unroll
  for (int i = 0; i < 4; ++i) ON.u[i] = 0x3F803F80u;

  f32x4 o[2][4];
  #pragma unroll
  for (int qg = 0; qg < 2; ++qg)
    #pragma unroll
    for (int m = 0; m < 4; ++m) o[qg][m] = f32x4{0.f, 0.f, 0.f, 0.f};
  f32x4 ls0 = f32x4{0.f, 0.f, 0.f, 0.f};   // l accumulator qg0 (rows identical)
  f32x4 ls1 = f32x4{0.f, 0.f, 0.f, 0.f};   // l accumulator qg1

  const u16* kb_g = k  + (long)b * Tn * Hn;
  const u16* vb_g = vt + (long)b * Hn * Tn;

  // staging: 16B granule-XOR folded into per-lane GLOBAL source (rule #21)
  const int g0 = t, g1 = 256 + t;
  const int r0g = g0 >> 3, c0g = g0 & 7;
  const int r1g = g1 >> 3, c1g = g1 & 7;
  const long ksrc0 = (long)r0g * Hn + ((c0g ^ (r0g & 7)) << 3);
  const long ksrc1 = (long)r1g * Hn + ((c1g ^ (r1g & 7)) << 3);
  const long vsrc0 = (long)r0g * Tn + ((c0g ^ (r0g & 7)) << 3);
  const long vsrc1 = (long)r1g * Tn + ((c1g ^ (r1g & 7)) << 3);
  const int wb0 = w * 64 * 8;
  const int wb1 = wb0 + 256 * 8;

  // fragment-read swizzle
  const int swz  = l15 & 7;
  const int cks0 = ((0 * 4 + lh) ^ swz) << 3;
  const int cks1 = ((1 * 4 + lh) ^ swz) << 3;
  const int rfr  = l15 * 64;

  // prologue: stage tiles it0 -> buf0 and it0+1 -> buf1
  {
    const u16* kt = kb_g + (long)it0 * 64 * Hn;
    const u16* vp = vb_g + it0 * 64;
    gl16(kt + ksrc0, &kbuf[0][wb0]);
    gl16(kt + ksrc1, &kbuf[0][wb1]);
    gl16(vp + vsrc0, &vbuf[0][wb0]);
    gl16(vp + vsrc1, &vbuf[0][wb1]);
    const u16* kt1 = kb_g + (long)(it0 + 1) * 64 * Hn;
    const u16* vp1 = vb_g + (it0 + 1) * 64;
    gl16(kt1 + ksrc0, &kbuf[1][wb0]);
    gl16(kt1 + ksrc1, &kbuf[1][wb1]);
    gl16(vp1 + vsrc0, &vbuf[1][wb0]);
    gl16(vp1 + vsrc1, &vbuf[1][wb1]);
  }
  asm volatile("s_waitcnt vmcnt(4)" ::: "memory");   // tile it0 landed
  __builtin_amdgcn_s_barrier();
  __builtin_amdgcn_sched_barrier(0);

  for (int it = it0; it < it1; ++it) {
    const int cb = (it - it0) % 3;
    const int sb = (it - it0 + 2) % 3;
    if (it + 2 < it1) {
      const u16* kt = kb_g + (long)(it + 2) * 64 * Hn;
      const u16* vp = vb_g + (it + 2) * 64;
      gl16(kt + ksrc0, &kbuf[sb][wb0]);
      gl16(kt + ksrc1, &kbuf[sb][wb1]);
      gl16(vp + vsrc0, &vbuf[sb][wb0]);
      gl16(vp + vsrc1, &vbuf[sb][wb1]);
    }

    const u16* kc  = &kbuf[cb][0];
    const u16* vcb = &vbuf[cb][0];

    // S^T = K Q^T for both q-groups; each K-frag read ONCE
    f32x4 s0[4], s1[4];
    #pragma unroll
    for (int n = 0; n < 4; ++n) { s0[n] = f32x4{0.f,0.f,0.f,0.f}; s1[n] = f32x4{0.f,0.f,0.f,0.f}; }
    #pragma unroll
    for (int n = 0; n < 4; ++n) {
      const short8 ak0 = *reinterpret_cast<const short8*>(&kc[n * 1024 + rfr + cks0]);
      const short8 ak1 = *reinterpret_cast<const short8*>(&kc[n * 1024 + rfr + cks1]);
      s0[n] = MFMA16(ak0, aq[0][0], s0[n]);
      s0[n] = MFMA16(ak1, aq[0][1], s0[n]);
      s1[n] = MFMA16(ak0, aq[1][0], s1[n]);
      s1[n] = MFMA16(ak1, aq[1][1], s1[n]);
    }

    // P = exp2(S) in-register (max-free)
    #pragma unroll
    for (int n = 0; n < 4; ++n)
      #pragma unroll
      for (int r = 0; r < 4; ++r) {
        s0[n][r] = __builtin_amdgcn_exp2f(s0[n][r]);
        s1[n][r] = __builtin_amdgcn_exp2f(s1[n][r]);
      }

    union { short8 s8; uint32_t u[4]; } B00, B01, B10, B11;
    B00.u[0] = pkbf(s0[0][0], s0[0][1]); B00.u[1] = pkbf(s0[0][2], s0[0][3]);
    B00.u[2] = pkbf(s0[1][0], s0[1][1]); B00.u[3] = pkbf(s0[1][2], s0[1][3]);
    B01.u[0] = pkbf(s0[2][0], s0[2][1]); B01.u[1] = pkbf(s0[2][2], s0[2][3]);
    B01.u[2] = pkbf(s0[3][0], s0[3][1]); B01.u[3] = pkbf(s0[3][2], s0[3][3]);
    B10.u[0] = pkbf(s1[0][0], s1[0][1]); B10.u[1] = pkbf(s1[0][2], s1[0][3]);
    B10.u[2] = pkbf(s1[1][0], s1[1][1]); B10.u[3] = pkbf(s1[1][2], s1[1][3]);
    B11.u[0] = pkbf(s1[2][0], s1[2][1]); B11.u[1] = pkbf(s1[2][2], s1[2][3]);
    B11.u[2] = pkbf(s1[3][0], s1[3][1]); B11.u[3] = pkbf(s1[3][2], s1[3][3]);

    // O^T += V'^T P^T ; l += ones x P (matrix pipe, no VALU row-sum)
    #pragma unroll
    for (int m = 0; m < 4; ++m) {
      const short8 av0 = *reinterpret_cast<const short8*>(&vcb[m * 1024 + rfr + cks0]);
      const short8 av1 = *reinterpret_cast<const short8*>(&vcb[m * 1024 + rfr + cks1]);
      o[0][m] = MFMA16(av0, B00.s8, o[0][m]);
      o[0][m] = MFMA16(av1, B01.s8, o[0][m]);
      o[1][m] = MFMA16(av0, B10.s8, o[1][m]);
      o[1][m] = MFMA16(av1, B11.s8, o[1][m]);
    }
    ls0 = MFMA16(ON.s8, B00.s8, ls0);
    ls0 = MFMA16(ON.s8, B01.s8, ls0);
    ls1 = MFMA16(ON.s8, B10.s8, ls1);
    ls1 = MFMA16(ON.s8, B11.s8, ls1);

    if (it + 1 < it1) {
      // only tile it+1's (older) loads must land; newest 4 may stay in flight
      if (it + 2 < it1) asm volatile("s_waitcnt vmcnt(4)" ::: "memory");
      else              asm volatile("s_waitcnt vmcnt(0)" ::: "memory");
      __builtin_amdgcn_s_barrier();
      __builtin_amdgcn_sched_barrier(0);
    }
  }

  // epilogue: l is already the full per-q sum in every lane (row 0 of ls)
  #pragma unroll
  for (int qg = 0; qg < 2; ++qg) {
    const float tot = (qg == 0) ? ls0[0] : ls1[0];
    const long qrow = rowbase + w * 32 + qg * 16 + l15;
    float* od = opart + ((long)split * NELT) + qrow * Hn;
    #pragma unroll
    for (int m = 0; m < 4; ++m) {
      float4 vv;
      vv.x = o[qg][m][0]; vv.y = o[qg][m][1]; vv.z = o[qg][m][2]; vv.w = o[qg][m][3];
      *reinterpret_cast<float4*>(od + m * 16 + lh * 4) = vv;
    }
    if (lh == 0) lpart[(long)split * NTOK + qrow] = tot;
  }
}

// ---------------------------------------------------------------------------
// Kernel 3: combine split-K partials: out = (sum O_s) / (sum l_s)
// ---------------------------------------------------------------------------
__global__ __launch_bounds__(256) void combine(
    const float* __restrict__ op, const float* __restrict__ lp,
    float* __restrict__ out)
{
  const long idx  = (long)blockIdx.x * 256 + threadIdx.x;
  const long base = idx * 4;
  const long row  = base >> 6;
  float4 acc = *reinterpret_cast<const float4*>(op + base);
  float lsum = lp[row];
  #pragma unroll
  for (int s = 1; s < SPLITS; ++s) {
    const float4 c = *reinterpret_cast<const float4*>(op + s * NELT + base);
    acc.x += c.x; acc.y += c.y; acc.z += c.z; acc.w += c.w;
    lsum += lp[s * NTOK + row];
  }
  const float linv = 1.0f / lsum;
  float4 r;
  r.x = acc.x * linv; r.y = acc.y * linv; r.z = acc.z * linv; r.w = acc.w * linv;
  *reinterpret_cast<float4*>(out + base) = r;
}

// ---------------------------------------------------------------------------
extern "C" void kernel_launch(void* const* d_in, const int* in_sizes, int n_in,
                              void* d_out, int out_size, void* d_ws, size_t ws_size,
                              hipStream_t stream) {
  const float* x  = (const float*)d_in[0];
  const float* Wq = (const float*)d_in[1];
  const float* bq = (const float*)d_in[2];
  const float* Wk = (const float*)d_in[3];
  const float* bk = (const float*)d_in[4];
  const float* Wv = (const float*)d_in[5];
  const float* bv = (const float*)d_in[6];
  float* out = (float*)d_out;

  u16* qs  = (u16*)d_ws;                         // [32768][64] bf16, pre-scaled
  u16* ks  = qs + NELT;                          // [32768][64] bf16
  u16* vs  = ks + NELT;                          // V^T [16][64][2048] bf16 (PI-slot order)
  u16* wtd = vs + NELT;                          // WT [3][64][384] bf16
  float* op = (float*)(wtd + 3 * 64 * Cn);       // O partials [SPLITS][32768][64]
  float* lp = op + (long)SPLITS * NELT;          // l partials [SPLITS][32768]

  hipLaunchKernelGGL(wtrans, dim3(18), dim3(256), 0, stream, Wq, Wk, Wv, wtd);
  hipLaunchKernelGGL(qkv_proj, dim3((int)(NTOK / 64)), dim3(256), 0, stream,
                     x, wtd, bq, bk, bv, qs, ks, vs);
  hipLaunchKernelGGL(flash_attn, dim3(16 * 16 * SPLITS), dim3(256), 0, stream,
                     qs, ks, vs, op, lp);
  hipLaunchKernelGGL(combine, dim3((int)(NELT / 4 / 256)), dim3(256), 0, stream,
                     op, lp, out);
}